// Round 1
// baseline (323.416 us; speedup 1.0000x reference)
//
#include <hip/hip_runtime.h>

typedef __attribute__((ext_vector_type(8))) short short8;
typedef __attribute__((ext_vector_type(4))) float f32x4;

#define NN 90
#define FD 32

__device__ inline unsigned short f2bf(float f) {
  unsigned u = __builtin_bit_cast(unsigned, f);
  unsigned r = (u + 0x7fffu + ((u >> 16) & 1u)) >> 16;
  return (unsigned short)r;
}
__device__ inline float bf2f(unsigned short h) {
  unsigned u = ((unsigned)h) << 16;
  return __builtin_bit_cast(float, u);
}
__device__ inline f32x4 mfma16(short8 a, short8 b, f32x4 c) {
  return __builtin_amdgcn_mfma_f32_16x16x32_bf16(a, b, c, 0, 0, 0);
}

__global__ __launch_bounds__(256) void CAI_35141422416140_kernel(
    const float* __restrict__ sc, const float* __restrict__ fc,
    const float* __restrict__ we, float* __restrict__ out, int nb)
{
  const int b   = blockIdx.x;
  const int tid = threadIdx.x;
  const int w   = tid >> 6;
  const int l   = tid & 63;
  const int lg  = l >> 4;
  const int lj  = l & 15;

  __shared__ __align__(16) char lds[64000];
  unsigned short* Shi = (unsigned short*)(lds + 0);      // [96][40]
  unsigned short* Slo = (unsigned short*)(lds + 7680);
  unsigned short* Fhi = (unsigned short*)(lds + 15360);
  unsigned short* Flo = (unsigned short*)(lds + 23040);
  unsigned short* Ghi = (unsigned short*)(lds + 30720);
  unsigned short* Glo = (unsigned short*)(lds + 38400);
  unsigned short* E1T = (unsigned short*)(lds + 0);      // [96][104] overlay (phase>=4)
  unsigned short* ERm = (unsigned short*)(lds + 19968);  // [96][104] overlay
  unsigned short* St  = (unsigned short*)(lds + 46080);  // [32][104]
  unsigned short* Ft  = (unsigned short*)(lds + 52736);  // [32][104]
  float* part1 = (float*)(lds + 59392);                  // [4][96]
  float* part2 = (float*)(lds + 60928);                  // [4][96]
  float* cmaxA = (float*)(lds + 62464);                  // [96]
  float* rmaxA = (float*)(lds + 62848);                  // [96]
  float* icsum = (float*)(lds + 63232);                  // [96]
  float* irsum = (float*)(lds + 63616);                  // [96]

  // W B-fragments for G = F*W : B[k=e][j=d], lane j=lj+16*nt, k=lg*8+e
  short8 Wh[2], Wl[2];
  #pragma unroll
  for (int nt = 0; nt < 2; ++nt) {
    #pragma unroll
    for (int e = 0; e < 8; ++e) {
      float wv = we[(lg*8 + e)*32 + nt*16 + lj];
      unsigned short h = f2bf(wv);
      Wh[nt][e] = (short)h;
      Wl[nt][e] = (short)f2bf(wv - bf2f(h));
    }
  }

  // P1: load S,F (f32, coalesced), split hi/lo, stage LDS (+ transposed copies)
  const float* Sg = sc + (size_t)b * (NN*FD);
  const float* Fg = fc + (size_t)b * (NN*FD);
  #pragma unroll
  for (int s = 0; s < 12; ++s) {
    int flat = s*256 + tid;          // 0..3071  (96 rows x 32 cols)
    int n = flat >> 5, d = flat & 31;
    float sv = (n < NN) ? Sg[flat] : 0.f;
    float fv = (n < NN) ? Fg[flat] : 0.f;
    unsigned short sh = f2bf(sv);
    unsigned short fh = f2bf(fv);
    Shi[n*40+d] = sh; Slo[n*40+d] = f2bf(sv - bf2f(sh));
    Fhi[n*40+d] = fh; Flo[n*40+d] = f2bf(fv - bf2f(fh));
    St[d*104+n] = sh;
    Ft[d*104+n] = fh;
  }
  __syncthreads();

  // P2: G = F*W  [96][32], split-precision (3 MFMA), write hi/lo
  for (int rep = 0; rep < 2; ++rep) {
    int mt = rep ? (w + 4) : w;
    if (mt > 5) break;
    short8 fh8 = *(const short8*)&Fhi[(mt*16+lj)*40 + lg*8];
    short8 fl8 = *(const short8*)&Flo[(mt*16+lj)*40 + lg*8];
    #pragma unroll
    for (int nt = 0; nt < 2; ++nt) {
      f32x4 g = {0.f,0.f,0.f,0.f};
      g = mfma16(fh8, Wh[nt], g);
      g = mfma16(fh8, Wl[nt], g);
      g = mfma16(fl8, Wh[nt], g);
      #pragma unroll
      for (int q = 0; q < 4; ++q) {
        int row = mt*16 + lg*4 + q;
        unsigned short gh = f2bf(g[q]);
        Ghi[row*40 + nt*16 + lj] = gh;
        Glo[row*40 + nt*16 + lj] = f2bf(g[q] - bf2f(gh));
      }
    }
  }
  __syncthreads();

  // P3: A = S*G^T, 36 tiles (6n x 6m), 9 per wave, acc stays in registers
  f32x4 acc[9];
  short8 sh8, sl8;
  int cur_nt = -1;
  #pragma unroll
  for (int i = 0; i < 9; ++i) {
    int t6 = 9*w + i;
    int nt = t6 / 6;
    int mt = t6 % 6;
    if (nt != cur_nt) {
      sh8 = *(const short8*)&Shi[(nt*16+lj)*40 + lg*8];
      sl8 = *(const short8*)&Slo[(nt*16+lj)*40 + lg*8];
      cur_nt = nt;
    }
    short8 gh8 = *(const short8*)&Ghi[(mt*16+lj)*40 + lg*8];
    short8 gl8 = *(const short8*)&Glo[(mt*16+lj)*40 + lg*8];
    f32x4 a = {0.f,0.f,0.f,0.f};
    a = mfma16(sh8, gh8, a);
    a = mfma16(sh8, gl8, a);
    a = mfma16(sl8, gh8, a);
    acc[i] = a;
  }

  // P4a: per-wave column-max partials (reduce over n) and row-max partials (over m)
  #pragma unroll
  for (int mt = 0; mt < 6; ++mt) {
    float cm = -1e30f;
    #pragma unroll
    for (int i = 0; i < 9; ++i) {
      if ((3*w + i) % 6 == mt) {
        f32x4 a = acc[i];
        cm = fmaxf(cm, fmaxf(fmaxf(a[0],a[1]), fmaxf(a[2],a[3])));
      }
    }
    cm = fmaxf(cm, __shfl_xor(cm, 16));
    cm = fmaxf(cm, __shfl_xor(cm, 32));
    if (l < 16) part1[w*96 + mt*16 + l] = cm;
  }
  #pragma unroll
  for (int nt = 0; nt < 6; ++nt) {
    f32x4 rm = {-1e30f,-1e30f,-1e30f,-1e30f};
    #pragma unroll
    for (int i = 0; i < 9; ++i) {
      if ((9*w + i) / 6 == nt) {
        f32x4 a = acc[i];
        rm[0] = fmaxf(rm[0], a[0]); rm[1] = fmaxf(rm[1], a[1]);
        rm[2] = fmaxf(rm[2], a[2]); rm[3] = fmaxf(rm[3], a[3]);
      }
    }
    #pragma unroll
    for (int q = 0; q < 4; ++q) {
      float v = rm[q];
      v = fmaxf(v, __shfl_xor(v, 1));
      v = fmaxf(v, __shfl_xor(v, 2));
      v = fmaxf(v, __shfl_xor(v, 4));
      v = fmaxf(v, __shfl_xor(v, 8));
      rm[q] = v;
    }
    if (lj < 4) {
      float v = rm[0];
      if (lj == 1) v = rm[1];
      if (lj == 2) v = rm[2];
      if (lj == 3) v = rm[3];
      part2[w*96 + nt*16 + lg*4 + lj] = v;
    }
  }
  __syncthreads();

  // P4b: final max, then zero the partial buffers for the sum pass
  if (tid < 96) {
    float c = fmaxf(fmaxf(part1[tid], part1[96+tid]), fmaxf(part1[192+tid], part1[288+tid]));
    cmaxA[tid] = c;
    float r = fmaxf(fmaxf(part2[tid], part2[96+tid]), fmaxf(part2[192+tid], part2[288+tid]));
    rmaxA[tid] = r;
    part1[tid] = 0.f; part1[96+tid] = 0.f; part1[192+tid] = 0.f; part1[288+tid] = 0.f;
    part2[tid] = 0.f; part2[96+tid] = 0.f; part2[192+tid] = 0.f; part2[288+tid] = 0.f;
  }
  __syncthreads();

  // P4c: e1 = exp(A - cmax[m]) -> E1T[m][n] (bf16), col sums
  #pragma unroll
  for (int mt = 0; mt < 6; ++mt) {
    float cs = 0.f;
    float cm = cmaxA[mt*16 + lj];
    #pragma unroll
    for (int i = 0; i < 9; ++i) {
      if ((3*w + i) % 6 == mt) {
        int nt = (9*w + i) / 6;
        f32x4 a = acc[i];
        #pragma unroll
        for (int q = 0; q < 4; ++q) {
          int n = nt*16 + lg*4 + q;
          float e = (n < NN) ? __expf(a[q] - cm) : 0.f;
          E1T[(mt*16+lj)*104 + n] = f2bf(e);
          cs += e;
        }
      }
    }
    cs += __shfl_xor(cs, 16);
    cs += __shfl_xor(cs, 32);
    if (l < 16) part1[w*96 + mt*16 + l] = cs;
  }
  // P4d: eR = exp(A - rmax[n]) -> ERm[n][m] (bf16), row sums
  #pragma unroll
  for (int nt = 0; nt < 6; ++nt) {
    f32x4 rs = {0.f,0.f,0.f,0.f};
    float rm0 = rmaxA[nt*16 + lg*4 + 0];
    float rm1 = rmaxA[nt*16 + lg*4 + 1];
    float rm2 = rmaxA[nt*16 + lg*4 + 2];
    float rm3 = rmaxA[nt*16 + lg*4 + 3];
    #pragma unroll
    for (int i = 0; i < 9; ++i) {
      if ((9*w + i) / 6 == nt) {
        int mt = (3*w + i) % 6;
        int m = mt*16 + lj;
        f32x4 a = acc[i];
        float e0 = (m < NN) ? __expf(a[0] - rm0) : 0.f;
        float e1 = (m < NN) ? __expf(a[1] - rm1) : 0.f;
        float e2 = (m < NN) ? __expf(a[2] - rm2) : 0.f;
        float e3 = (m < NN) ? __expf(a[3] - rm3) : 0.f;
        ERm[(nt*16+lg*4+0)*104 + m] = f2bf(e0);
        ERm[(nt*16+lg*4+1)*104 + m] = f2bf(e1);
        ERm[(nt*16+lg*4+2)*104 + m] = f2bf(e2);
        ERm[(nt*16+lg*4+3)*104 + m] = f2bf(e3);
        rs[0] += e0; rs[1] += e1; rs[2] += e2; rs[3] += e3;
      }
    }
    #pragma unroll
    for (int q = 0; q < 4; ++q) {
      float v = rs[q];
      v += __shfl_xor(v, 1);
      v += __shfl_xor(v, 2);
      v += __shfl_xor(v, 4);
      v += __shfl_xor(v, 8);
      rs[q] = v;
    }
    if (lj < 4) {
      float v = rs[0];
      if (lj == 1) v = rs[1];
      if (lj == 2) v = rs[2];
      if (lj == 3) v = rs[3];
      part2[w*96 + nt*16 + lg*4 + lj] = v;
    }
  }
  __syncthreads();

  if (tid < 96) {
    float cs = part1[tid] + part1[96+tid] + part1[192+tid] + part1[288+tid];
    icsum[tid] = 1.f / cs;
    float rsv = part2[tid] + part2[96+tid] + part2[192+tid] + part2[288+tid];
    irsum[tid] = 1.f / rsv;
  }
  __syncthreads();

  // P5: cosc = (1/csum[m]) * E1T[m][:] . S[:][d]   and   cofc = (1/rsum[n]) * ER[n][:] . F[:][d]
  const size_t obase1 = (size_t)b * (NN*FD);
  const size_t obase2 = (size_t)nb * (NN*FD) + obase1;
  #pragma unroll
  for (int i = 0; i < 3; ++i) {
    int t5 = 3*w + i;
    int mt = t5 >> 1, dt = t5 & 1;
    f32x4 o = {0.f,0.f,0.f,0.f};
    #pragma unroll
    for (int ks = 0; ks < 3; ++ks) {
      short8 af = *(const short8*)&E1T[(mt*16+lj)*104 + ks*32 + lg*8];
      short8 bf = *(const short8*)&St [(dt*16+lj)*104 + ks*32 + lg*8];
      o = mfma16(af, bf, o);
    }
    #pragma unroll
    for (int q = 0; q < 4; ++q) {
      int m = mt*16 + lg*4 + q;
      if (m < NN) out[obase1 + m*FD + dt*16 + lj] = o[q] * icsum[m];
    }
  }
  #pragma unroll
  for (int i = 0; i < 3; ++i) {
    int t5 = 3*w + i;
    int ntt = t5 >> 1, dt = t5 & 1;
    f32x4 o = {0.f,0.f,0.f,0.f};
    #pragma unroll
    for (int ks = 0; ks < 3; ++ks) {
      short8 af = *(const short8*)&ERm[(ntt*16+lj)*104 + ks*32 + lg*8];
      short8 bf = *(const short8*)&Ft [(dt*16+lj)*104 + ks*32 + lg*8];
      o = mfma16(af, bf, o);
    }
    #pragma unroll
    for (int q = 0; q < 4; ++q) {
      int n = ntt*16 + lg*4 + q;
      if (n < NN) out[obase2 + n*FD + dt*16 + lj] = o[q] * irsum[n];
    }
  }
}

extern "C" void kernel_launch(void* const* d_in, const int* in_sizes, int n_in,
                              void* d_out, int out_size, void* d_ws, size_t ws_size,
                              hipStream_t stream) {
  const float* sc = (const float*)d_in[0];
  const float* fc = (const float*)d_in[1];
  const float* we = (const float*)d_in[2];
  float* out = (float*)d_out;
  int nb = in_sizes[0] / (NN*FD);   // 8192
  CAI_35141422416140_kernel<<<dim3(nb), dim3(256), 0, stream>>>(sc, fc, we, out, nb);
}

// Round 2
// 238.062 us; speedup vs baseline: 1.3585x; 1.3585x over previous
//
#include <hip/hip_runtime.h>

typedef __attribute__((ext_vector_type(8))) short short8;
typedef __attribute__((ext_vector_type(4))) short short4v;
typedef __attribute__((ext_vector_type(4))) float f32x4;

#define NN 90
#define FD 32

__device__ inline unsigned short f2bf(float f) {
  unsigned u = __builtin_bit_cast(unsigned, f);
  return (unsigned short)((u + 0x7fffu + ((u >> 16) & 1u)) >> 16);
}
__device__ inline float bf2f(unsigned short h) {
  unsigned u = ((unsigned)h) << 16;
  return __builtin_bit_cast(float, u);
}
__device__ inline unsigned short lo_of(float v, unsigned short h) {
  float r = v - bf2f(h);
  return (unsigned short)(__builtin_bit_cast(unsigned, r) >> 16);  // trunc is fine for lo
}
__device__ inline f32x4 mfma16(short8 a, short8 b, f32x4 c) {
  return __builtin_amdgcn_mfma_f32_16x16x32_bf16(a, b, c, 0, 0, 0);
}
// build hi/lo bf16 A/B fragment from 8 consecutive f32 (16B-aligned)
__device__ inline void frag_f32(const float* p, short8& hi, short8& lo) {
  f32x4 a = *(const f32x4*)p;
  f32x4 b = *(const f32x4*)(p + 4);
  float v[8] = {a[0], a[1], a[2], a[3], b[0], b[1], b[2], b[3]};
  #pragma unroll
  for (int i = 0; i < 8; ++i) {
    unsigned short h = f2bf(v[i]);
    hi[i] = (short)h;
    lo[i] = (short)lo_of(v[i], h);
  }
}

__global__ __launch_bounds__(256, 4) void CAI_35141422416140_kernel(
    const float* __restrict__ sc, const float* __restrict__ fc,
    const float* __restrict__ we, float* __restrict__ out, int nb)
{
  const int b   = blockIdx.x;
  const int tid = threadIdx.x;
  const int w   = tid >> 6;
  const int l   = tid & 63;
  const int lg  = l >> 4;
  const int lj  = l & 15;

  // LDS: 33280 B -> 4 blocks/CU (16 waves, 50% occupancy)
  __shared__ __align__(16) char lds[33280];
  unsigned short* St  = (unsigned short*)(lds + 0);      // [32][104] S^T bf16-hi
  unsigned short* Ft  = (unsigned short*)(lds + 6656);   // [32][104]
  unsigned short* Ghi = (unsigned short*)(lds + 13312);  // [96][40]
  unsigned short* Glo = (unsigned short*)(lds + 20992);  // [96][40]
  unsigned short* E   = (unsigned short*)(lds + 13312);  // [96][104] overlays G (phase>=4)

  const float* Sg = sc + (size_t)b * (NN * FD);
  const float* Fg = fc + (size_t)b * (NN * FD);

  // P0: W B-fragments (hi/lo), B[k=e][j=d], lane j = lj+16*nt, k = lg*8+e
  short8 Wh[2], Wl[2];
  #pragma unroll
  for (int nt = 0; nt < 2; ++nt) {
    #pragma unroll
    for (int e = 0; e < 8; ++e) {
      float wv = we[(lg * 8 + e) * FD + nt * 16 + lj];
      unsigned short h = f2bf(wv);
      Wh[nt][e] = (short)h;
      Wl[nt][e] = (short)lo_of(wv, h);
    }
  }

  // P1: coalesced float4 loads -> transposed bf16 St/Ft only
  #pragma unroll
  for (int s = 0; s < 3; ++s) {
    int idx  = s * 256 + tid;      // 0..767
    int flat = idx * 4;            // 0..3068
    int n = flat >> 5, d = flat & 31;
    if (n < NN) {
      f32x4 sv = *(const f32x4*)(Sg + flat);
      f32x4 fv = *(const f32x4*)(Fg + flat);
      #pragma unroll
      for (int j = 0; j < 4; ++j) {
        St[(d + j) * 104 + n] = f2bf(sv[j]);
        Ft[(d + j) * 104 + n] = f2bf(fv[j]);
      }
    } else {  // zero-pad rows 90..95 (k goes to 95 in P5 MFMAs)
      #pragma unroll
      for (int j = 0; j < 4; ++j) {
        St[(d + j) * 104 + n] = 0;
        Ft[(d + j) * 104 + n] = 0;
      }
    }
  }

  // P2: G = F*W (split precision, 3 MFMA), F rows loaded per-lane from global
  #pragma unroll
  for (int rep = 0; rep < 2; ++rep) {
    int mt = w + rep * 4;
    if (mt <= 5) {
      int row = mt * 16 + lj; if (row > NN - 1) row = NN - 1;  // clamp (finite pad)
      short8 fh, fl;
      frag_f32(Fg + row * FD + lg * 8, fh, fl);
      #pragma unroll
      for (int nt = 0; nt < 2; ++nt) {
        f32x4 g = {0.f, 0.f, 0.f, 0.f};
        g = mfma16(fh, Wh[nt], g);
        g = mfma16(fh, Wl[nt], g);
        g = mfma16(fl, Wh[nt], g);
        #pragma unroll
        for (int q = 0; q < 4; ++q) {
          int grow = mt * 16 + lg * 4 + q;
          unsigned short gh = f2bf(g[q]);
          Ghi[grow * 40 + nt * 16 + lj] = gh;
          Glo[grow * 40 + nt * 16 + lj] = lo_of(g[q], gh);
        }
      }
    }
  }
  __syncthreads();

  // P3: A = S*G^T, 9 tiles/wave, acc in registers; S rows loaded per-lane
  f32x4 acc[9];
  short8 sh8, sl8;
  int cur_nt = -1;
  #pragma unroll
  for (int i = 0; i < 9; ++i) {
    int t6 = 9 * w + i;
    int nt = t6 / 6, mt = t6 % 6;
    if (nt != cur_nt) {
      int row = nt * 16 + lj; if (row > NN - 1) row = NN - 1;
      frag_f32(Sg + row * FD + lg * 8, sh8, sl8);
      cur_nt = nt;
    }
    short8 gh8 = *(const short8*)&Ghi[(mt * 16 + lj) * 40 + lg * 8];
    short8 gl8 = *(const short8*)&Glo[(mt * 16 + lj) * 40 + lg * 8];
    f32x4 a = {0.f, 0.f, 0.f, 0.f};
    a = mfma16(sh8, gh8, a);
    a = mfma16(sh8, gl8, a);
    a = mfma16(sl8, gh8, a);
    acc[i] = a;
  }
  __syncthreads();  // G dead; E overlay safe

  // P4: acc = exp(acc) in place (no max-sub needed; |A|<~35), write E1T[m][n]
  #pragma unroll
  for (int i = 0; i < 9; ++i) {
    int t6 = 9 * w + i;
    int nt = t6 / 6, mt = t6 % 6;
    f32x4 a = acc[i];
    #pragma unroll
    for (int q = 0; q < 4; ++q) a[q] = __expf(a[q]);
    acc[i] = a;  // keep exp values for ERm pass
    short4v pk;
    #pragma unroll
    for (int q = 0; q < 4; ++q) {
      int n = nt * 16 + lg * 4 + q;
      pk[q] = (short)((n < NN) ? f2bf(a[q]) : (unsigned short)0);
    }
    *(short4v*)&E[(mt * 16 + lj) * 104 + nt * 16 + lg * 4] = pk;
  }
  __syncthreads();

  const short ONE = (short)0x3F80;  // bf16 1.0
  const short8 ones = {ONE, ONE, ONE, ONE, ONE, ONE, ONE, ONE};

  // P5a: cosc[m][d] = sum_n E1T[m][n]*S[n][d] / csum[m]; csum via ones-MFMA
  {
    const size_t ob1 = (size_t)b * (NN * FD);
    f32x4 inv; int curmt = -1;
    #pragma unroll
    for (int i = 0; i < 3; ++i) {
      int t5 = 3 * w + i;
      int mt = t5 >> 1, dt = t5 & 1;
      bool newmt = (mt != curmt);
      f32x4 o = {0.f, 0.f, 0.f, 0.f};
      f32x4 s4 = {0.f, 0.f, 0.f, 0.f};
      #pragma unroll
      for (int ks = 0; ks < 3; ++ks) {
        short8 af = *(const short8*)&E [(mt * 16 + lj) * 104 + ks * 32 + lg * 8];
        short8 bf = *(const short8*)&St[(dt * 16 + lj) * 104 + ks * 32 + lg * 8];
        o = mfma16(af, bf, o);
        if (newmt) s4 = mfma16(af, ones, s4);
      }
      if (newmt) {
        #pragma unroll
        for (int q = 0; q < 4; ++q) inv[q] = 1.0f / s4[q];
        curmt = mt;
      }
      #pragma unroll
      for (int q = 0; q < 4; ++q) {
        int m = mt * 16 + lg * 4 + q;
        if (m < NN) out[ob1 + m * FD + dt * 16 + lj] = o[q] * inv[q];
      }
    }
  }
  __syncthreads();  // all E1T reads done

  // P4d: overwrite E with ERm[n][m] (zero cols m>=NN)
  #pragma unroll
  for (int i = 0; i < 9; ++i) {
    int t6 = 9 * w + i;
    int nt = t6 / 6, mt = t6 % 6;
    int m = mt * 16 + lj;
    f32x4 a = acc[i];
    #pragma unroll
    for (int q = 0; q < 4; ++q) {
      E[(nt * 16 + lg * 4 + q) * 104 + m] =
          (m < NN) ? f2bf(a[q]) : (unsigned short)0;
    }
  }
  __syncthreads();

  // P5b: cofc[n][d] = sum_m ERm[n][m]*F[m][d] / rsum[n]; rsum via ones-MFMA
  {
    const size_t ob2 = (size_t)nb * (NN * FD) + (size_t)b * (NN * FD);
    f32x4 inv; int curnt = -1;
    #pragma unroll
    for (int i = 0; i < 3; ++i) {
      int t5 = 3 * w + i;
      int ntt = t5 >> 1, dt = t5 & 1;
      bool newnt = (ntt != curnt);
      f32x4 o = {0.f, 0.f, 0.f, 0.f};
      f32x4 s4 = {0.f, 0.f, 0.f, 0.f};
      #pragma unroll
      for (int ks = 0; ks < 3; ++ks) {
        short8 af = *(const short8*)&E [(ntt * 16 + lj) * 104 + ks * 32 + lg * 8];
        short8 bf = *(const short8*)&Ft[(dt * 16 + lj) * 104 + ks * 32 + lg * 8];
        o = mfma16(af, bf, o);
        if (newnt) s4 = mfma16(af, ones, s4);
      }
      if (newnt) {
        #pragma unroll
        for (int q = 0; q < 4; ++q) inv[q] = 1.0f / s4[q];
        curnt = ntt;
      }
      #pragma unroll
      for (int q = 0; q < 4; ++q) {
        int n = ntt * 16 + lg * 4 + q;
        if (n < NN) out[ob2 + n * FD + dt * 16 + lj] = o[q] * inv[q];
      }
    }
  }
}

extern "C" void kernel_launch(void* const* d_in, const int* in_sizes, int n_in,
                              void* d_out, int out_size, void* d_ws, size_t ws_size,
                              hipStream_t stream) {
  const float* sc = (const float*)d_in[0];
  const float* fc = (const float*)d_in[1];
  const float* we = (const float*)d_in[2];
  float* out = (float*)d_out;
  int nb = in_sizes[0] / (NN * FD);  // 8192
  CAI_35141422416140_kernel<<<dim3(nb), dim3(256), 0, stream>>>(sc, fc, we, out, nb);
}

// Round 3
// 150.687 us; speedup vs baseline: 2.1463x; 1.5798x over previous
//
#include <hip/hip_runtime.h>

typedef __attribute__((ext_vector_type(8))) short short8;
typedef __attribute__((ext_vector_type(4))) short short4v;
typedef __attribute__((ext_vector_type(4))) float f32x4;

#define NN 90
#define FD 32

__device__ inline unsigned short f2bf(float f) {
  unsigned u = __builtin_bit_cast(unsigned, f);
  return (unsigned short)((u + 0x7fffu + ((u >> 16) & 1u)) >> 16);
}
__device__ inline float bf2f(unsigned short h) {
  unsigned u = ((unsigned)h) << 16;
  return __builtin_bit_cast(float, u);
}
__device__ inline unsigned short lo_of(float v, unsigned short h) {
  float r = v - bf2f(h);
  return (unsigned short)(__builtin_bit_cast(unsigned, r) >> 16);
}
__device__ inline f32x4 mfma16(short8 a, short8 b, f32x4 c) {
  return __builtin_amdgcn_mfma_f32_16x16x32_bf16(a, b, c, 0, 0, 0);
}
// hi/lo bf16 fragment from 8 consecutive f32 (16B-aligned)
__device__ inline void frag_f32(const float* p, short8& hi, short8& lo) {
  f32x4 a = *(const f32x4*)p;
  f32x4 b = *(const f32x4*)(p + 4);
  float v[8] = {a[0], a[1], a[2], a[3], b[0], b[1], b[2], b[3]};
  #pragma unroll
  for (int i = 0; i < 8; ++i) {
    unsigned short h = f2bf(v[i]);
    hi[i] = (short)h;
    lo[i] = (short)lo_of(v[i], h);
  }
}

__global__ __launch_bounds__(256, 3) void CAI_35141422416140_kernel(
    const float* __restrict__ sc, const float* __restrict__ fc,
    const float* __restrict__ we, float* __restrict__ out, int nb)
{
  const int b   = blockIdx.x;
  const int tid = threadIdx.x;
  const int w   = tid >> 6;
  const int l   = tid & 63;
  const int lg  = l >> 4;
  const int lj  = l & 15;

  // LDS 50752 B -> 3 blocks/CU (12 waves)
  __shared__ __align__(16) char lds[50752];
  unsigned short* St  = (unsigned short*)(lds + 0);      // [32][104]
  unsigned short* Ft  = (unsigned short*)(lds + 6656);   // [32][104]
  unsigned short* Ghi = (unsigned short*)(lds + 13312);  // [96][40]
  unsigned short* Glo = (unsigned short*)(lds + 20992);  // [96][40]
  unsigned short* E1T = (unsigned short*)(lds + 13312);  // [90][104] overlays G after P3
  unsigned short* ERm = (unsigned short*)(lds + 32032);  // [90][104]

  const float* Sg = sc + (size_t)b * (NN * FD);
  const float* Fg = fc + (size_t)b * (NN * FD);

  // P1: transposed bf16 staging, b64 LDS writes, coalesced scalar loads
  #pragma unroll
  for (int s = 0; s < 3; ++s) {
    int u  = s * 256 + tid;        // 0..767 = 32 d x 24 n-quads
    int d  = u & 31;
    int n0 = (u >> 5) * 4;         // 0..92
    short4v sp, fp;
    #pragma unroll
    for (int r = 0; r < 4; ++r) {
      bool ok = (n0 + r) < NN;
      float sv = ok ? Sg[(n0 + r) * FD + d] : 0.f;
      float fv = ok ? Fg[(n0 + r) * FD + d] : 0.f;
      sp[r] = (short)f2bf(sv);
      fp[r] = (short)f2bf(fv);
    }
    *(short4v*)&St[d * 104 + n0] = sp;
    *(short4v*)&Ft[d * 104 + n0] = fp;
  }

  // P0: W B-fragments (hi/lo), lane j = lj+16*nt, k = lg*8+e
  short8 Wh[2], Wl[2];
  #pragma unroll
  for (int nt = 0; nt < 2; ++nt) {
    #pragma unroll
    for (int e = 0; e < 8; ++e) {
      float wv = we[(lg * 8 + e) * FD + nt * 16 + lj];
      unsigned short h = f2bf(wv);
      Wh[nt][e] = (short)h;
      Wl[nt][e] = (short)lo_of(wv, h);
    }
  }

  // P2: G = F*W (split precision), F rows per-lane from global
  #pragma unroll
  for (int rep = 0; rep < 2; ++rep) {
    int mt = w + rep * 4;
    if (mt <= 5) {
      int row = mt * 16 + lj; if (row > NN - 1) row = NN - 1;
      short8 fh, fl;
      frag_f32(Fg + row * FD + lg * 8, fh, fl);
      #pragma unroll
      for (int nt = 0; nt < 2; ++nt) {
        f32x4 g = {0.f, 0.f, 0.f, 0.f};
        g = mfma16(fh, Wh[nt], g);
        g = mfma16(fh, Wl[nt], g);
        g = mfma16(fl, Wh[nt], g);
        #pragma unroll
        for (int q = 0; q < 4; ++q) {
          int grow = mt * 16 + lg * 4 + q;
          unsigned short gh = f2bf(g[q]);
          Ghi[grow * 40 + nt * 16 + lj] = gh;
          Glo[grow * 40 + nt * 16 + lj] = lo_of(g[q], gh);
        }
      }
    }
  }
  __syncthreads();

  // P3: dual pass — A[nt,mt] and AT[mt,nt] from the SAME register fragments
  f32x4 a_acc[9], t_acc[9];
  short8 sh8, sl8;
  int cur_nt = -1;
  #pragma unroll
  for (int i = 0; i < 9; ++i) {
    int t6 = 9 * w + i;
    int nt = t6 / 6, mt = t6 % 6;
    if (nt != cur_nt) {
      int row = nt * 16 + lj; if (row > NN - 1) row = NN - 1;
      frag_f32(Sg + row * FD + lg * 8, sh8, sl8);
      cur_nt = nt;
    }
    short8 gh8 = *(const short8*)&Ghi[(mt * 16 + lj) * 40 + lg * 8];
    short8 gl8 = *(const short8*)&Glo[(mt * 16 + lj) * 40 + lg * 8];
    f32x4 a = {0.f, 0.f, 0.f, 0.f};
    a = mfma16(sh8, gh8, a);
    a = mfma16(sh8, gl8, a);
    a = mfma16(sl8, gh8, a);
    a_acc[i] = a;
    f32x4 t = {0.f, 0.f, 0.f, 0.f};
    t = mfma16(gh8, sh8, t);
    t = mfma16(gh8, sl8, t);
    t = mfma16(gl8, sh8, t);
    t_acc[i] = t;
  }
  __syncthreads();  // all G reads done; E1T overlay safe

  // P4: exp + b64 writes of BOTH layouts (no transpose scatter)
  #pragma unroll
  for (int i = 0; i < 9; ++i) {
    int t6 = 9 * w + i;
    int nt = t6 / 6, mt = t6 % 6;
    f32x4 a = a_acc[i], t = t_acc[i];
    #pragma unroll
    for (int q = 0; q < 4; ++q) { a[q] = __expf(a[q]); t[q] = __expf(t[q]); }
    int rowm = mt * 16 + lj;           // E1T row = m
    if (rowm < NN) {
      short4v pk;
      #pragma unroll
      for (int q = 0; q < 4; ++q) {
        int n = nt * 16 + lg * 4 + q;
        pk[q] = (short)((n < NN) ? f2bf(a[q]) : (unsigned short)0);
      }
      *(short4v*)&E1T[rowm * 104 + nt * 16 + lg * 4] = pk;
    }
    int rown = nt * 16 + lj;           // ERm row = n
    if (rown < NN) {
      short4v pk;
      #pragma unroll
      for (int q = 0; q < 4; ++q) {
        int m = mt * 16 + lg * 4 + q;
        pk[q] = (short)((m < NN) ? f2bf(t[q]) : (unsigned short)0);
      }
      *(short4v*)&ERm[rown * 104 + mt * 16 + lg * 4] = pk;
    }
  }
  __syncthreads();

  const short ONE = (short)0x3F80;  // bf16 1.0
  const short8 ones = {ONE, ONE, ONE, ONE, ONE, ONE, ONE, ONE};
  const size_t ob1 = (size_t)b * (NN * FD);
  const size_t ob2 = (size_t)nb * (NN * FD) + ob1;

  // P5a: cosc[m][d] = sum_n E1T[m][n]*S[n][d] / csum[m]
  {
    f32x4 inv; int curmt = -1;
    #pragma unroll
    for (int i = 0; i < 3; ++i) {
      int t5 = 3 * w + i;
      int mt = t5 >> 1, dt = t5 & 1;
      bool newmt = (mt != curmt);
      int arow = mt * 16 + lj; if (arow > NN - 1) arow = NN - 1;
      f32x4 o = {0.f, 0.f, 0.f, 0.f};
      f32x4 s4 = {0.f, 0.f, 0.f, 0.f};
      #pragma unroll
      for (int ks = 0; ks < 3; ++ks) {
        short8 af = *(const short8*)&E1T[arow * 104 + ks * 32 + lg * 8];
        short8 bf = *(const short8*)&St [(dt * 16 + lj) * 104 + ks * 32 + lg * 8];
        o = mfma16(af, bf, o);
        if (newmt) s4 = mfma16(af, ones, s4);
      }
      if (newmt) {
        #pragma unroll
        for (int q = 0; q < 4; ++q) inv[q] = 1.0f / s4[q];
        curmt = mt;
      }
      #pragma unroll
      for (int q = 0; q < 4; ++q) {
        int m = mt * 16 + lg * 4 + q;
        if (m < NN) out[ob1 + m * FD + dt * 16 + lj] = o[q] * inv[q];
      }
    }
  }

  // P5b: cofc[n][d] = sum_m ERm[n][m]*F[m][d] / rsum[n]   (no barrier needed)
  {
    f32x4 inv; int curnt = -1;
    #pragma unroll
    for (int i = 0; i < 3; ++i) {
      int t5 = 3 * w + i;
      int ntt = t5 >> 1, dt = t5 & 1;
      bool newnt = (ntt != curnt);
      int arow = ntt * 16 + lj; if (arow > NN - 1) arow = NN - 1;
      f32x4 o = {0.f, 0.f, 0.f, 0.f};
      f32x4 s4 = {0.f, 0.f, 0.f, 0.f};
      #pragma unroll
      for (int ks = 0; ks < 3; ++ks) {
        short8 af = *(const short8*)&ERm[arow * 104 + ks * 32 + lg * 8];
        short8 bf = *(const short8*)&Ft [(dt * 16 + lj) * 104 + ks * 32 + lg * 8];
        o = mfma16(af, bf, o);
        if (newnt) s4 = mfma16(af, ones, s4);
      }
      if (newnt) {
        #pragma unroll
        for (int q = 0; q < 4; ++q) inv[q] = 1.0f / s4[q];
        curnt = ntt;
      }
      #pragma unroll
      for (int q = 0; q < 4; ++q) {
        int n = ntt * 16 + lg * 4 + q;
        if (n < NN) out[ob2 + n * FD + dt * 16 + lj] = o[q] * inv[q];
      }
    }
  }
}

extern "C" void kernel_launch(void* const* d_in, const int* in_sizes, int n_in,
                              void* d_out, int out_size, void* d_ws, size_t ws_size,
                              hipStream_t stream) {
  const float* sc = (const float*)d_in[0];
  const float* fc = (const float*)d_in[1];
  const float* we = (const float*)d_in[2];
  float* out = (float*)d_out;
  int nb = in_sizes[0] / (NN * FD);  // 8192
  CAI_35141422416140_kernel<<<dim3(nb), dim3(256), 0, stream>>>(sc, fc, we, out, nb);
}